// Round 8
// baseline (490.771 us; speedup 1.0000x reference)
//
#include <hip/hip_runtime.h>

// B=1024, H=56, J=64, N=56, I=64.
// t4[b,i,m,n] = sum_{k,j} x[b, m+k-1, j, n] * W2[i,k,j]   (zero-padded in h)
// y[b,i,m,(n+1)%56] = t4[b,i,m,n]*W1[i,0] + t4[b,i,(m-1)%56,n]*W1[i,1]
//
// Folded 4-tap: y[i,m,c] = sum_{k'} W2'[i,k',j] * x[m-2+k', j, (c-1)%56]
//   W2' = [bW0, aW0+bW1, aW1+bW2, aW2]; zero-pad slices handled by SKIPPING
//   taps (m=1 skips k'=0, m=55 skips k'=3) -> no zero slices stored.
//   m=0 (circular) uses W2'' = [bW0, bW1, aW1, aW2] over x54,x55,x0,x1.
//
// Structure: block = (batch, 14-row m-chunk, n-half). Stage ALL 17 tap
// slices (28 source cols x 64 j, bf16) into LDS once -> ONE barrier ->
// compute 14 rows barrier-free. 2 blocks/CU co-residency hides staging.
// XCD swizzle puts a batch's 8 blocks on one XCD (halo + sectors hit L2).

#define ROWE 1096   // ushorts per n-row: 17 slots * 64 + 8 pad (2192 B)

typedef __attribute__((ext_vector_type(8))) short short8_t;
typedef __attribute__((ext_vector_type(4))) float f32x4;

__device__ __forceinline__ unsigned short f2bf(float f) {
  union { float f; unsigned u; } v; v.f = f;
  return (unsigned short)((v.u + 0x7FFFu + ((v.u >> 16) & 1u)) >> 16);
}

// ---- pre-kernel: merged 4-tap weight sets (bf16) into ws ----
__global__ void prep_weights(const float* __restrict__ W1,
                             const float* __restrict__ W2,
                             unsigned short* __restrict__ wp) {
  const int t = threadIdx.x;            // 256 threads
  const int i = t >> 2;
  const int j0 = (t & 3) * 16;
  const float a = W1[i * 2 + 0], b = W1[i * 2 + 1];
  const float* w = W2 + i * 192;
  unsigned short* p0 = wp + i * 256;            // W2'  (m = 1..55)
  unsigned short* p1 = wp + 16384 + i * 256;    // W2'' (m = 0 wrap)
  for (int j = j0; j < j0 + 16; ++j) {
    const float w0 = w[j], w1 = w[64 + j], w2 = w[128 + j];
    p0[j]       = f2bf(b * w0);
    p0[64 + j]  = f2bf(a * w0 + b * w1);
    p0[128 + j] = f2bf(a * w1 + b * w2);
    p0[192 + j] = f2bf(a * w2);
    p1[j]       = f2bf(b * w0);
    p1[64 + j]  = f2bf(b * w1);
    p1[128 + j] = f2bf(a * w1);
    p1[192 + j] = f2bf(a * w2);
  }
}

// one output row m: acc over MFMA steps s in [SBEG,SEND), slots l0+(s>>1)
template<int SBEG, int SEND>
__device__ __forceinline__ void dorow(const short8_t* af,
                                      const unsigned short* sm, int rbase,
                                      int l0, float* ob, int m, bool act) {
  f32x4 acc = {0.f, 0.f, 0.f, 0.f};
  #pragma unroll
  for (int s = SBEG; s < SEND; ++s) {
    const int off = (l0 + (s >> 1)) * 64 + (s & 1) * 32;
    const short8_t bf = *(const short8_t*)&sm[rbase + off];
    acc = __builtin_amdgcn_mfma_f32_16x16x32_bf16(af[s], bf, acc, 0, 0, 0);
  }
  if (act) {
    float* pm = ob + m * 56;
    #pragma unroll
    for (int r = 0; r < 4; ++r) pm[r * 3136] = acc[r];
  }
}

__global__ __launch_bounds__(512, 4) void conv4tap(
    const float* __restrict__ x, const unsigned short* __restrict__ wp,
    float* __restrict__ out) {
  __shared__ unsigned short sm[28 * ROWE];   // 61376 B -> 2 blocks/CU

  const int tid = threadIdx.x;
  const int bid = blockIdx.x;
  // bijective swizzle: all 8 blocks of a batch land on one XCD (bid%8 const)
  const int batch = (bid & 7) * 128 + (bid >> 6);
  const int sub   = (bid >> 3) & 7;
  const int chunk = sub >> 1;          // m-chunk: rows 14*chunk..+13
  const int half  = sub & 1;           // source cols 28*half..+27
  const int NS    = (chunk == 3) ? 16 : 17;
  const int hb    = 14 * chunk - 2;

  const float* __restrict__ xb = x + (size_t)batch * (56 * 64 * 56);

  const int wave = tid >> 6, lane = tid & 63;
  const int lq = lane & 15, lg = lane >> 4;
  const int iw = wave >> 1, ct = wave & 1;

  // ---- A fragments: W2' (64 x 256 bf16), i = 16*iw + lq ----
  short8_t afrag[8];
  {
    const unsigned short* ap = wp + ((16 * iw + lq) << 8) + lg * 8;
    #pragma unroll
    for (int s = 0; s < 8; ++s) afrag[s] = *(const short8_t*)(ap + s * 32);
  }

  // ---- staging: 448 workers = n-quad(7) x j(64); 1 float4 + 4 b16 writes ----
  const bool stg = tid < 448;
  const int t7 = tid % 7;
  const int js = tid / 7;
  const float* const xcol = xb + (size_t)js * 56 + 28 * half + 4 * t7;
  unsigned short* const wb = &sm[(4 * t7) * ROWE + js];

  auto hmap = [&](int s) -> int {
    return (chunk == 0) ? (s < 2 ? 54 + s : s - 2) : (hb + s);
  };
  float4 Ra, Rb, Rc;
  auto issue = [&](int s, float4& R) {
    if (stg && s < NS) R = *(const float4*)(xcol + (size_t)hmap(s) * 3584);
  };
  auto put = [&](int s, const float4& R) {
    if (stg && s < NS) {
      wb[0 * ROWE + s * 64] = f2bf(R.x);
      wb[1 * ROWE + s * 64] = f2bf(R.y);
      wb[2 * ROWE + s * 64] = f2bf(R.z);
      wb[3 * ROWE + s * 64] = f2bf(R.w);
    }
  };

  issue(0, Ra); issue(1, Rb); issue(2, Rc);
  #pragma unroll 1
  for (int s = 0; s < 15; s += 3) {          // puts 0..14, issues 3..16
    put(s, Ra);     issue(s + 3, Ra);
    put(s + 1, Rb); issue(s + 4, Rb);
    put(s + 2, Rc); issue(s + 5, Rc);
  }
  put(15, Ra); put(16, Rb);

  __syncthreads();

  // ---- compute: wave (iw, ct); col c = 28*half + 1 + 16*ct + lq (mod 56) ----
  const int lr0  = ct ? 16 + lq : lq;
  const int lrow = lr0 > 27 ? 27 : lr0;      // clamp inactive lanes in-bounds
  const int rbase = lrow * ROWE + lg * 8;
  const bool act = (ct == 0) || (lq < 12);
  const int c = (28 * half + 1 + 16 * ct + lq) % 56;
  float* const ob = out + (size_t)(batch * 64 + 16 * iw + 4 * lg) * 3136 + c;

  if (chunk == 0) {
    // slots: 0=x54, 1=x55, 2..16=x0..x14
    dorow<2, 8>(afrag, sm, rbase, 1, ob, 1, act);        // m=1 skips tap0
    #pragma unroll
    for (int r = 2; r <= 13; ++r)
      dorow<0, 8>(afrag, sm, rbase, r, ob, r, act);
    const unsigned short* ap2 = wp + 16384 + ((16 * iw + lq) << 8) + lg * 8;
    #pragma unroll
    for (int s = 0; s < 8; ++s) afrag[s] = *(const short8_t*)(ap2 + s * 32);
    dorow<0, 8>(afrag, sm, rbase, 0, ob, 0, act);        // m=0 wrap (W2'')
  } else if (chunk == 3) {
    // slots 0..15 = x40..x55
    #pragma unroll
    for (int r = 0; r < 13; ++r)
      dorow<0, 8>(afrag, sm, rbase, r, ob, 42 + r, act);
    dorow<0, 6>(afrag, sm, rbase, 13, ob, 55, act);      // m=55 skips tap3
  } else {
    // slots 0..16 = x[14*chunk-2 .. 14*chunk+14]
    const int m0 = 14 * chunk;
    #pragma unroll
    for (int r = 0; r < 14; ++r)
      dorow<0, 8>(afrag, sm, rbase, r, ob, m0 + r, act);
  }
}

extern "C" void kernel_launch(void* const* d_in, const int* in_sizes, int n_in,
                              void* d_out, int out_size, void* d_ws, size_t ws_size,
                              hipStream_t stream) {
  const float* x  = (const float*)d_in[0];
  const float* W1 = (const float*)d_in[1];
  const float* W2 = (const float*)d_in[2];
  float* out = (float*)d_out;
  unsigned short* wp = (unsigned short*)d_ws;
  prep_weights<<<1, 256, 0, stream>>>(W1, W2, wp);
  conv4tap<<<8192, 512, 0, stream>>>(x, wp, out);
}